// Round 1
// baseline (776.748 us; speedup 1.0000x reference)
//
#include <hip/hip_runtime.h>

typedef __bf16 bf16x8 __attribute__((ext_vector_type(8)));
typedef float f32x4 __attribute__((ext_vector_type(4)));

static __device__ __forceinline__ ushort f2b(float f) {
    uint32_t x = __float_as_uint(f);
    x += 0x7fffu + ((x >> 16) & 1u);   // RNE (finite values)
    return (ushort)(x >> 16);
}
static __device__ __forceinline__ float b2f(ushort u) {
    return __uint_as_float(((uint32_t)u) << 16);
}

// ---------------------------------------------------------------------------
// 1) adaptive_avg_pool2d(x, 3): one block per (b,c) plane. 96x96 -> 3x3.
//    Per bin: 32 rows x 8 float4 = 256 float4 -> exactly one per thread.
__global__ __launch_bounds__(256) void pool_k(const float* __restrict__ x,
                                              float* __restrict__ pooled) {
    const int bc  = blockIdx.x;
    const int tid = threadIdx.x;
    const int lane = tid & 63, wv = tid >> 6;
    const float4* p4 = (const float4*)(x + (size_t)bc * 9216);
    __shared__ float red[4][9];
#pragma unroll
    for (int bi = 0; bi < 3; ++bi) {
#pragma unroll
        for (int bj = 0; bj < 3; ++bj) {
            int row = bi * 32 + (tid >> 3);
            int c4  = bj * 8 + (tid & 7);
            float4 f = p4[row * 24 + c4];
            float s = f.x + f.y + f.z + f.w;
#pragma unroll
            for (int off = 32; off; off >>= 1) s += __shfl_down(s, off);
            if (lane == 0) red[wv][bi * 3 + bj] = s;
        }
    }
    __syncthreads();
    if (tid < 9) {
        float s = red[0][tid] + red[1][tid] + red[2][tid] + red[3][tid];
        pooled[(size_t)bc * 9 + tid] = s * (1.0f / 1024.0f);
    }
}

// ---------------------------------------------------------------------------
// 2) gen = einsum('bcij,oc->boij', pooled, w_gen) + b_gen
//    grid = B*9 blocks, 256 threads (one per output channel o)
__global__ __launch_bounds__(256) void gen_k(const float* __restrict__ pooled,
                                             const float* __restrict__ wgen,
                                             const float* __restrict__ bgen,
                                             float* __restrict__ gen) {
    __shared__ float pl[256];
    const int b = blockIdx.x / 9, ij = blockIdx.x % 9;
    const int o = threadIdx.x;
    pl[o] = pooled[((size_t)b * 256 + o) * 9 + ij];
    __syncthreads();
    float a = bgen[o];
    const float4* wg4 = (const float4*)(wgen + (size_t)o * 256);
    const float4* pl4 = (const float4*)pl;
#pragma unroll 4
    for (int q = 0; q < 64; ++q) {
        float4 w = wg4[q], p = pl4[q];
        a += w.x * p.x + w.y * p.y + w.z * p.z + w.w * p.w;
    }
    gen[((size_t)b * 256 + o) * 9 + ij] = a;
}

// ---------------------------------------------------------------------------
// 3) weight transpose+convert: wtr[(tap*256 + o)*256 + c] = bf16(w_c1[o][c][tap])
__global__ __launch_bounds__(256) void wtr_k(const float* __restrict__ wc1,
                                             ushort* __restrict__ wtr) {
    int i = blockIdx.x * 256 + threadIdx.x;   // < 589824
    int tap = i >> 16;
    int rem = i & 65535;                      // o*256 + c
    wtr[i] = f2b(wc1[(size_t)rem * 9 + tap]);
}

// ---------------------------------------------------------------------------
// 4) conv3x3 (C=256 -> 256) as implicit GEMM, bf16 MFMA 16x16x32.
//    One WG per (b, h-row): all 256 out-ch x 96 px. 512 thr = 8 waves (4m x 2n).
//    K-loop: 9 taps x 8 c-blocks of 32. A = weights [o][c], B = shifted rows.
__global__ __launch_bounds__(512) void conv_k(const float* __restrict__ xin,
                                              const ushort* __restrict__ wtr,
                                              const float* __restrict__ bc1,
                                              ushort* __restrict__ yb) {
    __shared__ ushort Al[256 * 48];   // [o][c_local], row stride 48 (16B aligned)
    __shared__ ushort Bl[96 * 48];    // [px][c_local]

    const int blk = blockIdx.x;
    const int b = blk / 96, h = blk % 96;
    const int tid = threadIdx.x;
    const int lane = tid & 63, wv = tid >> 6;
    const int wm = wv & 3, wn = wv >> 2;
    const int lo = lane & 15, hi = lane >> 4;

    f32x4 acc[4][3] = {};

    // A-staging: thread -> (row o = tid>>1, half = tid&1), 8 dwords each
    const int ao = tid >> 1, ah = tid & 1;
    uint32_t* Ad = (uint32_t*)Al + ao * 24 + ah * 8;
    const uint32_t abase = (uint32_t)ao * 128 + (uint32_t)ah * 8;

    // B-staging thread->element map (constant across steps)
    int kcs[6], pxs[6], boff[6];
    size_t goff[6];
#pragma unroll
    for (int it = 0; it < 6; ++it) {
        int lin = tid + it * 512;          // 0..3071
        int kc = lin / 96, px = lin - kc * 96;
        kcs[it] = kc; pxs[it] = px;
        boff[it] = px * 48 + kc;
        goff[it] = (size_t)kc * 9216 + px;
    }

    // fragment LDS pointers (constant per thread)
    const bf16x8* pA[4];
    const bf16x8* pB[3];
#pragma unroll
    for (int mi = 0; mi < 4; ++mi)
        pA[mi] = (const bf16x8*)&Al[(wm * 64 + mi * 16 + lo) * 48 + hi * 8];
#pragma unroll
    for (int ni = 0; ni < 3; ++ni)
        pB[ni] = (const bf16x8*)&Bl[(wn * 48 + ni * 16 + lo) * 48 + hi * 8];

    for (int tap = 0; tap < 9; ++tap) {
        const int dy = tap / 3, dx = tap % 3;
        const int r = h + dy - 1;
        if (r < 0 || r >= 96) continue;    // whole tap contributes zero
        const float* xtap = xin + (size_t)b * 2359296 + (size_t)r * 96 + (dx - 1);
        bool colok[6];
#pragma unroll
        for (int it = 0; it < 6; ++it) {
            int col = pxs[it] + dx - 1;
            colok[it] = ((unsigned)col < 96u);
        }
        const uint32_t* Atap = (const uint32_t*)wtr + (size_t)tap * 32768 + abase;

        for (int c0 = 0; c0 < 256; c0 += 32) {
            __syncthreads();
            // stage A tile: 256 x 32 bf16
            const uint32_t* Ag = Atap + (c0 >> 1);
#pragma unroll
            for (int j = 0; j < 8; ++j) Ad[j] = Ag[j];
            // stage B tile: 32 (c) x 96 (px), shifted row, f32 -> bf16
            const float* xg = xtap + (size_t)c0 * 9216;
#pragma unroll
            for (int it = 0; it < 6; ++it) {
                ushort u = 0;
                if (colok[it]) u = f2b(xg[goff[it]]);
                Bl[boff[it]] = u;
            }
            __syncthreads();

            bf16x8 af[4], bfr[3];
#pragma unroll
            for (int mi = 0; mi < 4; ++mi) af[mi] = pA[mi][0];
#pragma unroll
            for (int ni = 0; ni < 3; ++ni) bfr[ni] = pB[ni][0];
#pragma unroll
            for (int mi = 0; mi < 4; ++mi)
#pragma unroll
                for (int ni = 0; ni < 3; ++ni)
                    acc[mi][ni] = __builtin_amdgcn_mfma_f32_16x16x32_bf16(
                        af[mi], bfr[ni], acc[mi][ni], 0, 0, 0);
        }
    }

    // epilogue: +bias, store y as bf16 (NCHW). D: col(px)=lane&15, row=(hi*4+rr)
    const size_t ybase = (size_t)b * 2359296 + (size_t)h * 96;
#pragma unroll
    for (int mi = 0; mi < 4; ++mi) {
        const int o0 = wm * 64 + mi * 16 + hi * 4;
#pragma unroll
        for (int rr = 0; rr < 4; ++rr) {
            const int o = o0 + rr;
            const float bias = bc1[o];
#pragma unroll
            for (int ni = 0; ni < 3; ++ni) {
                const int px = wn * 48 + ni * 16 + lo;
                float v = acc[mi][ni][rr] + bias;
                yb[ybase + (size_t)o * 9216 + px] = f2b(v);
            }
        }
    }
}

// ---------------------------------------------------------------------------
// 5) BN stats: per-(b,c) partial sum/sumsq of y (deterministic, no atomics)
__global__ __launch_bounds__(256) void bnstat_k(const ushort* __restrict__ yb,
                                                float* __restrict__ part) {
    const int bc = blockIdx.x, tid = threadIdx.x;
    const ushort4* p4 = (const ushort4*)(yb + (size_t)bc * 9216);
    float s = 0.f, s2 = 0.f;
#pragma unroll
    for (int it = 0; it < 9; ++it) {
        ushort4 u = p4[tid + it * 256];
        float a = b2f(u.x), bb = b2f(u.y), c = b2f(u.z), d = b2f(u.w);
        s  += a + bb + c + d;
        s2 += a * a + bb * bb + c * c + d * d;
    }
    const int lane = tid & 63, wv = tid >> 6;
#pragma unroll
    for (int off = 32; off; off >>= 1) {
        s += __shfl_down(s, off);
        s2 += __shfl_down(s2, off);
    }
    __shared__ float r1[4], r2[4];
    if (lane == 0) { r1[wv] = s; r2[wv] = s2; }
    __syncthreads();
    if (tid == 0) part[bc]        = r1[0] + r1[1] + r1[2] + r1[3];
    if (tid == 1) part[4096 + bc] = r2[0] + r2[1] + r2[2] + r2[3];
}

// 6) finalize BN: scale/shift per channel
__global__ __launch_bounds__(256) void bnfin_k(const float* __restrict__ part,
                                               const float* __restrict__ gamma,
                                               const float* __restrict__ beta,
                                               float* __restrict__ bnp) {
    const int c = threadIdx.x;
    float s = 0.f, s2 = 0.f;
#pragma unroll
    for (int b = 0; b < 16; ++b) {
        s  += part[b * 256 + c];
        s2 += part[4096 + b * 256 + c];
    }
    const float invN = 1.0f / 147456.0f;
    float mu  = s * invN;
    float var = s2 * invN - mu * mu;
    float sc  = gamma[c] * rsqrtf(var + 1e-5f);
    bnp[c]       = sc;
    bnp[256 + c] = beta[c] - mu * sc;
}

// ---------------------------------------------------------------------------
// 7) depthwise 3x3 with per-(b,c) filters; BN+ReLU applied while staging plane
__global__ __launch_bounds__(256) void dw_k(const ushort* __restrict__ yb,
                                            const float* __restrict__ gen,
                                            const float* __restrict__ bnp,
                                            float* __restrict__ out) {
    __shared__ float pl[9216];
    const int bc = blockIdx.x, tid = threadIdx.x;
    const int c = bc & 255;
    const float sc = bnp[c], sh = bnp[256 + c];
    const ushort4* p4 = (const ushort4*)(yb + (size_t)bc * 9216);
#pragma unroll
    for (int it = 0; it < 9; ++it) {
        int v = tid + it * 256;
        ushort4 u = p4[v];
        float4 f;
        f.x = fmaxf(b2f(u.x) * sc + sh, 0.f);
        f.y = fmaxf(b2f(u.y) * sc + sh, 0.f);
        f.z = fmaxf(b2f(u.z) * sc + sh, 0.f);
        f.w = fmaxf(b2f(u.w) * sc + sh, 0.f);
        *(float4*)&pl[v * 4] = f;
    }
    float g[9];
    const float* gp = gen + (size_t)bc * 9;
#pragma unroll
    for (int k = 0; k < 9; ++k) g[k] = gp[k];
    __syncthreads();
    float* op = out + (size_t)bc * 9216;
#pragma unroll
    for (int it = 0; it < 36; ++it) {
        int i = tid + it * 256;
        int row = i / 96, col = i - row * 96;
        float a = 0.f;
#pragma unroll
        for (int dy = 0; dy < 3; ++dy) {
            int rr = row + dy - 1;
            if (rr < 0 || rr >= 96) continue;
#pragma unroll
            for (int dxq = 0; dxq < 3; ++dxq) {
                int cc = col + dxq - 1;
                if (cc < 0 || cc >= 96) continue;
                a += pl[rr * 96 + cc] * g[dy * 3 + dxq];
            }
        }
        op[i] = a;
    }
}

// ---------------------------------------------------------------------------
extern "C" void kernel_launch(void* const* d_in, const int* in_sizes, int n_in,
                              void* d_out, int out_size, void* d_ws, size_t ws_size,
                              hipStream_t stream) {
    const float* x       = (const float*)d_in[0];
    const float* conv_in = (const float*)d_in[1];
    const float* w_gen   = (const float*)d_in[2];
    const float* b_gen   = (const float*)d_in[3];
    const float* w_c1    = (const float*)d_in[4];
    const float* b_c1    = (const float*)d_in[5];
    const float* gamma   = (const float*)d_in[6];
    const float* beta    = (const float*)d_in[7];
    float* out = (float*)d_out;

    char* ws = (char*)d_ws;
    float*  pooled = (float*)(ws + 0);          // 147456 B
    float*  gen    = (float*)(ws + 147456);     // 147456 B
    ushort* wtr    = (ushort*)(ws + 294912);    // 1179648 B
    float*  part   = (float*)(ws + 1474560);    // 32768 B
    float*  bnp    = (float*)(ws + 1507328);    // 2048 B
    ushort* yb     = (ushort*)(ws + 1509376);   // 75497472 B  (total ~73.4 MB)

    pool_k  <<<4096, 256, 0, stream>>>(x, pooled);
    gen_k   <<<144,  256, 0, stream>>>(pooled, w_gen, b_gen, gen);
    wtr_k   <<<2304, 256, 0, stream>>>(w_c1, wtr);
    conv_k  <<<1536, 512, 0, stream>>>(conv_in, wtr, b_c1, yb);
    bnstat_k<<<4096, 256, 0, stream>>>(yb, part);
    bnfin_k <<<1,    256, 0, stream>>>(part, gamma, beta, bnp);
    dw_k    <<<4096, 256, 0, stream>>>(yb, gen, bnp, out);
}

// Round 2
// 583.828 us; speedup vs baseline: 1.3304x; 1.3304x over previous
//
#include <hip/hip_runtime.h>

typedef __bf16 bf16x8 __attribute__((ext_vector_type(8)));
typedef float f32x4 __attribute__((ext_vector_type(4)));

static __device__ __forceinline__ ushort f2b(float f) {
    uint32_t x = __float_as_uint(f);
    x += 0x7fffu + ((x >> 16) & 1u);   // RNE (finite values)
    return (ushort)(x >> 16);
}
static __device__ __forceinline__ float b2f(ushort u) {
    return __uint_as_float(((uint32_t)u) << 16);
}

// ---------------------------------------------------------------------------
// 1) adaptive_avg_pool2d(x, 3): one block per (b,c) plane. 96x96 -> 3x3.
__global__ __launch_bounds__(256) void pool_k(const float* __restrict__ x,
                                              float* __restrict__ pooled) {
    const int bc  = blockIdx.x;
    const int tid = threadIdx.x;
    const int lane = tid & 63, wv = tid >> 6;
    const float4* p4 = (const float4*)(x + (size_t)bc * 9216);
    __shared__ float red[4][9];
#pragma unroll
    for (int bi = 0; bi < 3; ++bi) {
#pragma unroll
        for (int bj = 0; bj < 3; ++bj) {
            int row = bi * 32 + (tid >> 3);
            int c4  = bj * 8 + (tid & 7);
            float4 f = p4[row * 24 + c4];
            float s = f.x + f.y + f.z + f.w;
#pragma unroll
            for (int off = 32; off; off >>= 1) s += __shfl_down(s, off);
            if (lane == 0) red[wv][bi * 3 + bj] = s;
        }
    }
    __syncthreads();
    if (tid < 9) {
        float s = red[0][tid] + red[1][tid] + red[2][tid] + red[3][tid];
        pooled[(size_t)bc * 9 + tid] = s * (1.0f / 1024.0f);
    }
}

// ---------------------------------------------------------------------------
// 2) gen = einsum('bcij,oc->boij', pooled, w_gen) + b_gen
__global__ __launch_bounds__(256) void gen_k(const float* __restrict__ pooled,
                                             const float* __restrict__ wgen,
                                             const float* __restrict__ bgen,
                                             float* __restrict__ gen) {
    __shared__ float pl[256];
    const int b = blockIdx.x / 9, ij = blockIdx.x % 9;
    const int o = threadIdx.x;
    pl[o] = pooled[((size_t)b * 256 + o) * 9 + ij];
    __syncthreads();
    float a = bgen[o];
    const float4* wg4 = (const float4*)(wgen + (size_t)o * 256);
    const float4* pl4 = (const float4*)pl;
#pragma unroll 4
    for (int q = 0; q < 64; ++q) {
        float4 w = wg4[q], p = pl4[q];
        a += w.x * p.x + w.y * p.y + w.z * p.z + w.w * p.w;
    }
    gen[((size_t)b * 256 + o) * 9 + ij] = a;
}

// ---------------------------------------------------------------------------
// 3) weight transpose+convert: wtr[(tap*256 + o)*256 + c] = bf16(w_c1[o][c][tap])
__global__ __launch_bounds__(256) void wtr_k(const float* __restrict__ wc1,
                                             ushort* __restrict__ wtr) {
    int i = blockIdx.x * 256 + threadIdx.x;   // < 589824
    int tap = i >> 16;
    int rem = i & 65535;                      // o*256 + c
    wtr[i] = f2b(wc1[(size_t)rem * 9 + tap]);
}

// ---------------------------------------------------------------------------
// 4) conv3x3 (C=256 -> 256) as implicit GEMM, bf16 MFMA 16x16x32.
//    One WG per (b, h): M=256 out-ch x N=96 px. 512 thr = 8 waves (4m x 2n).
//    Per c-chunk (32 ch): stage 3 halo rows into LDS once, then 9 taps of
//    MFMA with A fragments loaded straight from global (L2-resident wtr).
//    LDS B tile: [3 rows][98 px (zero-padded cols 0,97)][40 c-stride] bf16.
__global__ __launch_bounds__(512, 4) void conv_k(const float* __restrict__ xin,
                                                 const ushort* __restrict__ wtr,
                                                 const float* __restrict__ bc1,
                                                 ushort* __restrict__ yb) {
    __shared__ ushort Bl[3 * 98 * 40];   // 23520 B

    const int blk = blockIdx.x;
    const int b = blk / 96, h = blk % 96;
    const int tid = threadIdx.x;
    const int lane = tid & 63, wv = tid >> 6;
    const int wm = wv & 3, wn = wv >> 2;
    const int lo = lane & 15, hi = lane >> 4;

    f32x4 acc[4][3] = {};

    // ---- zero the px pad columns (store px 0 and 97), never overwritten
    if (tid < 192) {
        int row = tid >> 6, rem = tid & 63;
        int pxs = (rem >> 5) ? 97 : 0;
        int c   = rem & 31;
        Bl[(row * 98 + pxs) * 40 + c] = 0;
    }

    // ---- B staging map: 2304 float4 items (3 rows x 32 c x 24 px4)
    //      item -> (row, c, q): global float4 = x[b][c0+c][h+row-1][q*4..+3]
    bool act[5], vld[5];
    const float4* gsrc[5];
    int loff[5];
#pragma unroll
    for (int it = 0; it < 5; ++it) {
        int id = tid + it * 512;
        act[it] = (id < 2304);
        int idc = act[it] ? id : 0;
        int rc = idc / 24, q = idc - rc * 24;
        int row = rc >> 5, c = rc & 31;
        int r = h + row - 1;
        vld[it] = act[it] && ((unsigned)r < 96u);
        int rs = vld[it] ? r : 0;
        gsrc[it] = (const float4*)(xin + (size_t)b * 2359296 +
                                   (size_t)c * 9216 + (size_t)rs * 96 + q * 4);
        loff[it] = (row * 98 + q * 4 + 1) * 40 + c;
    }

    // ---- A fragment base offset (elements into wtr)
    const int abase = (wm * 64 + lo) * 256 + hi * 8;

    // ---- B fragment base (ushort index into Bl), before dy/dx/ni shifts
    const int bbase = (wn * 48 + lo + 1) * 40 + hi * 8;

    for (int c0 = 0; c0 < 256; c0 += 32) {
        if (c0) __syncthreads();           // previous compute done
        // stage 3 halo rows x 32 ch, f32 -> bf16, transposed to [px][c]
#pragma unroll
        for (int it = 0; it < 5; ++it) {
            if (!act[it]) continue;
            ushort u0 = 0, u1 = 0, u2 = 0, u3 = 0;
            if (vld[it]) {
                float4 f = gsrc[it][(size_t)(c0) * 2304];  // +c0*9216 floats
                u0 = f2b(f.x); u1 = f2b(f.y); u2 = f2b(f.z); u3 = f2b(f.w);
            }
            ushort* wp = &Bl[loff[it]];
            wp[0]   = u0;
            wp[40]  = u1;
            wp[80]  = u2;
            wp[120] = u3;
        }
        __syncthreads();

#pragma unroll
        for (int tap = 0; tap < 9; ++tap) {
            const int dy = tap / 3, dx = tap % 3;
            // A fragments from global (L2): rows = out-ch, cols = c0..c0+31
            const ushort* Ag = wtr + (size_t)tap * 65536 + abase + c0;
            bf16x8 af[4];
#pragma unroll
            for (int mi = 0; mi < 4; ++mi)
                af[mi] = *(const bf16x8*)(Ag + mi * 4096);
            // B fragments from LDS (shifted row/col)
            const ushort* Bp = &Bl[(size_t)dy * 3920 + bbase + (dx - 1) * 40];
            bf16x8 bfr[3];
#pragma unroll
            for (int ni = 0; ni < 3; ++ni)
                bfr[ni] = *(const bf16x8*)(Bp + ni * 640);
#pragma unroll
            for (int mi = 0; mi < 4; ++mi)
#pragma unroll
                for (int ni = 0; ni < 3; ++ni)
                    acc[mi][ni] = __builtin_amdgcn_mfma_f32_16x16x32_bf16(
                        af[mi], bfr[ni], acc[mi][ni], 0, 0, 0);
        }
    }

    // epilogue: +bias, store y as bf16 (NCHW). D: col(px)=lane&15, row=hi*4+rr
    const size_t ybase = (size_t)b * 2359296 + (size_t)h * 96;
#pragma unroll
    for (int mi = 0; mi < 4; ++mi) {
        const int o0 = wm * 64 + mi * 16 + hi * 4;
#pragma unroll
        for (int rr = 0; rr < 4; ++rr) {
            const int o = o0 + rr;
            const float bias = bc1[o];
#pragma unroll
            for (int ni = 0; ni < 3; ++ni) {
                const int px = wn * 48 + ni * 16 + lo;
                float v = acc[mi][ni][rr] + bias;
                yb[ybase + (size_t)o * 9216 + px] = f2b(v);
            }
        }
    }
}

// ---------------------------------------------------------------------------
// 5) BN stats: per-(b,c) partial sum/sumsq of y (deterministic, no atomics)
__global__ __launch_bounds__(256) void bnstat_k(const ushort* __restrict__ yb,
                                                float* __restrict__ part) {
    const int bc = blockIdx.x, tid = threadIdx.x;
    const ushort4* p4 = (const ushort4*)(yb + (size_t)bc * 9216);
    float s = 0.f, s2 = 0.f;
#pragma unroll
    for (int it = 0; it < 9; ++it) {
        ushort4 u = p4[tid + it * 256];
        float a = b2f(u.x), bb = b2f(u.y), c = b2f(u.z), d = b2f(u.w);
        s  += a + bb + c + d;
        s2 += a * a + bb * bb + c * c + d * d;
    }
    const int lane = tid & 63, wv = tid >> 6;
#pragma unroll
    for (int off = 32; off; off >>= 1) {
        s += __shfl_down(s, off);
        s2 += __shfl_down(s2, off);
    }
    __shared__ float r1[4], r2[4];
    if (lane == 0) { r1[wv] = s; r2[wv] = s2; }
    __syncthreads();
    if (tid == 0) part[bc]        = r1[0] + r1[1] + r1[2] + r1[3];
    if (tid == 1) part[4096 + bc] = r2[0] + r2[1] + r2[2] + r2[3];
}

// 6) finalize BN: scale/shift per channel
__global__ __launch_bounds__(256) void bnfin_k(const float* __restrict__ part,
                                               const float* __restrict__ gamma,
                                               const float* __restrict__ beta,
                                               float* __restrict__ bnp) {
    const int c = threadIdx.x;
    float s = 0.f, s2 = 0.f;
#pragma unroll
    for (int b = 0; b < 16; ++b) {
        s  += part[b * 256 + c];
        s2 += part[4096 + b * 256 + c];
    }
    const float invN = 1.0f / 147456.0f;
    float mu  = s * invN;
    float var = s2 * invN - mu * mu;
    float sc  = gamma[c] * rsqrtf(var + 1e-5f);
    bnp[c]       = sc;
    bnp[256 + c] = beta[c] - mu * sc;
}

// ---------------------------------------------------------------------------
// 7) depthwise 3x3 with per-(b,c) filters; BN+ReLU applied while staging plane
__global__ __launch_bounds__(256) void dw_k(const ushort* __restrict__ yb,
                                            const float* __restrict__ gen,
                                            const float* __restrict__ bnp,
                                            float* __restrict__ out) {
    __shared__ float pl[9216];
    const int bc = blockIdx.x, tid = threadIdx.x;
    const int c = bc & 255;
    const float sc = bnp[c], sh = bnp[256 + c];
    const ushort4* p4 = (const ushort4*)(yb + (size_t)bc * 9216);
#pragma unroll
    for (int it = 0; it < 9; ++it) {
        int v = tid + it * 256;
        ushort4 u = p4[v];
        float4 f;
        f.x = fmaxf(b2f(u.x) * sc + sh, 0.f);
        f.y = fmaxf(b2f(u.y) * sc + sh, 0.f);
        f.z = fmaxf(b2f(u.z) * sc + sh, 0.f);
        f.w = fmaxf(b2f(u.w) * sc + sh, 0.f);
        *(float4*)&pl[v * 4] = f;
    }
    float g[9];
    const float* gp = gen + (size_t)bc * 9;
#pragma unroll
    for (int k = 0; k < 9; ++k) g[k] = gp[k];
    __syncthreads();
    float* op = out + (size_t)bc * 9216;
#pragma unroll
    for (int it = 0; it < 36; ++it) {
        int i = tid + it * 256;
        int row = i / 96, col = i - row * 96;
        float a = 0.f;
#pragma unroll
        for (int dy = 0; dy < 3; ++dy) {
            int rr = row + dy - 1;
            if (rr < 0 || rr >= 96) continue;
#pragma unroll
            for (int dxq = 0; dxq < 3; ++dxq) {
                int cc = col + dxq - 1;
                if (cc < 0 || cc >= 96) continue;
                a += pl[rr * 96 + cc] * g[dy * 3 + dxq];
            }
        }
        op[i] = a;
    }
}

// ---------------------------------------------------------------------------
extern "C" void kernel_launch(void* const* d_in, const int* in_sizes, int n_in,
                              void* d_out, int out_size, void* d_ws, size_t ws_size,
                              hipStream_t stream) {
    const float* x       = (const float*)d_in[0];
    const float* conv_in = (const float*)d_in[1];
    const float* w_gen   = (const float*)d_in[2];
    const float* b_gen   = (const float*)d_in[3];
    const float* w_c1    = (const float*)d_in[4];
    const float* b_c1    = (const float*)d_in[5];
    const float* gamma   = (const float*)d_in[6];
    const float* beta    = (const float*)d_in[7];
    float* out = (float*)d_out;

    char* ws = (char*)d_ws;
    float*  pooled = (float*)(ws + 0);          // 147456 B
    float*  gen    = (float*)(ws + 147456);     // 147456 B
    ushort* wtr    = (ushort*)(ws + 294912);    // 1179648 B
    float*  part   = (float*)(ws + 1474560);    // 32768 B
    float*  bnp    = (float*)(ws + 1507328);    // 2048 B
    ushort* yb     = (ushort*)(ws + 1509376);   // 75497472 B  (total ~73.4 MB)

    pool_k  <<<4096, 256, 0, stream>>>(x, pooled);
    gen_k   <<<144,  256, 0, stream>>>(pooled, w_gen, b_gen, gen);
    wtr_k   <<<2304, 256, 0, stream>>>(w_c1, wtr);
    conv_k  <<<1536, 512, 0, stream>>>(conv_in, wtr, b_c1, yb);
    bnstat_k<<<4096, 256, 0, stream>>>(yb, part);
    bnfin_k <<<1,    256, 0, stream>>>(part, gamma, beta, bnp);
    dw_k    <<<4096, 256, 0, stream>>>(yb, gen, bnp, out);
}

// Round 3
// 375.783 us; speedup vs baseline: 2.0670x; 1.5536x over previous
//
#include <hip/hip_runtime.h>

typedef __bf16 bf16x8 __attribute__((ext_vector_type(8)));
typedef float f32x4 __attribute__((ext_vector_type(4)));

static __device__ __forceinline__ ushort f2b(float f) {
    uint32_t x = __float_as_uint(f);
    x += 0x7fffu + ((x >> 16) & 1u);   // RNE (finite values)
    return (ushort)(x >> 16);
}
static __device__ __forceinline__ float b2f(ushort u) {
    return __uint_as_float(((uint32_t)u) << 16);
}

typedef const __attribute__((address_space(1))) uint32_t gu32;
typedef __attribute__((address_space(3))) uint32_t lu32;
static __device__ __forceinline__ void gl_lds16(const void* g, void* l) {
    // async global->LDS, 16 B per lane; LDS dest = wave-uniform base + lane*16
    __builtin_amdgcn_global_load_lds((gu32*)g, (lu32*)l, 16, 0, 0);
}

// ---------------------------------------------------------------------------
// 1) adaptive_avg_pool2d(x, 3): one block per (b,c) plane. 96x96 -> 3x3.
__global__ __launch_bounds__(256) void pool_k(const float* __restrict__ x,
                                              float* __restrict__ pooled) {
    const int bc  = blockIdx.x;
    const int tid = threadIdx.x;
    const int lane = tid & 63, wv = tid >> 6;
    const float4* p4 = (const float4*)(x + (size_t)bc * 9216);
    __shared__ float red[4][9];
#pragma unroll
    for (int bi = 0; bi < 3; ++bi) {
#pragma unroll
        for (int bj = 0; bj < 3; ++bj) {
            int row = bi * 32 + (tid >> 3);
            int c4  = bj * 8 + (tid & 7);
            float4 f = p4[row * 24 + c4];
            float s = f.x + f.y + f.z + f.w;
#pragma unroll
            for (int off = 32; off; off >>= 1) s += __shfl_down(s, off);
            if (lane == 0) red[wv][bi * 3 + bj] = s;
        }
    }
    __syncthreads();
    if (tid < 9) {
        float s = red[0][tid] + red[1][tid] + red[2][tid] + red[3][tid];
        pooled[(size_t)bc * 9 + tid] = s * (1.0f / 1024.0f);
    }
}

// ---------------------------------------------------------------------------
// 2) gen = einsum('bcij,oc->boij', pooled, w_gen) + b_gen
__global__ __launch_bounds__(256) void gen_k(const float* __restrict__ pooled,
                                             const float* __restrict__ wgen,
                                             const float* __restrict__ bgen,
                                             float* __restrict__ gen) {
    __shared__ float pl[256];
    const int b = blockIdx.x / 9, ij = blockIdx.x % 9;
    const int o = threadIdx.x;
    pl[o] = pooled[((size_t)b * 256 + o) * 9 + ij];
    __syncthreads();
    float a = bgen[o];
    const float4* wg4 = (const float4*)(wgen + (size_t)o * 256);
    const float4* pl4 = (const float4*)pl;
#pragma unroll 4
    for (int q = 0; q < 64; ++q) {
        float4 w = wg4[q], p = pl4[q];
        a += w.x * p.x + w.y * p.y + w.z * p.z + w.w * p.w;
    }
    gen[((size_t)b * 256 + o) * 9 + ij] = a;
}

// ---------------------------------------------------------------------------
// 3) weight transpose+convert: wtr[(tap*256 + o)*256 + c] = bf16(w_c1[o][c][tap])
__global__ __launch_bounds__(256) void wtr_k(const float* __restrict__ wc1,
                                             ushort* __restrict__ wtr) {
    int i = blockIdx.x * 256 + threadIdx.x;   // < 589824
    int tap = i >> 16;
    int rem = i & 65535;                      // o*256 + c
    wtr[i] = f2b(wc1[(size_t)rem * 9 + tap]);
}

// ---------------------------------------------------------------------------
// 4) conv3x3 (C=256->256), implicit GEMM, MFMA 16x16x32 bf16.
//    Block = (b, 2 image rows). M=256 out-ch, N=192 px. 512 thr = 8 waves
//    (4m x 2n): wave = 64 ch x 96 px (one image row), acc[4][6].
//    K-loop: 72 steps (8 c-chunks x 9 taps). A-tile 256x32 double-buffered in
//    LDS via global_load_lds, prefetched 1 step ahead. B-halo tile
//    [4 rows][98 px][40 c] staged once per chunk (reg-staged, c-fast lanes ->
//    conflict-free writes), reused by all 9 taps.
__global__ __launch_bounds__(512) void conv_k(const float* __restrict__ xin,
                                              const ushort* __restrict__ wtr,
                                              const float* __restrict__ bc1,
                                              ushort* __restrict__ yb) {
    __shared__ ushort Al[2][8192];   // [buf][256 rows][32 c]  16 KB each
    __shared__ ushort Bl[15680];     // [4][98][40]            31360 B

    const int blk = blockIdx.x;
    const int b = blk / 48, hg = blk % 48, h0 = hg * 2;
    const int tid = threadIdx.x;
    const int lane = tid & 63, wv = tid >> 6;
    const int wm = wv & 3, wn = wv >> 2;
    const int lo = lane & 15, hi = lane >> 4;

    // zero px pad columns (px 0 and 97), all 4 rows, c 0..31
    if (tid < 256) {
        int row = tid >> 6, pxp = ((tid >> 5) & 1) ? 97 : 0, c = tid & 31;
        Bl[(row * 98 + pxp) * 40 + c] = 0;
    }

    // ---- A prefetch per-lane source offsets (LDS side is linear)
    const int arow = wv * 32 + (lane >> 2);
    const int acc_ = (lane & 3) * 8;
    const int aoff0 = arow * 256 + acc_;          // j=0
    const int aoff1 = aoff0 + 16 * 256;           // j=1 (rows +16)

    // ---- B staging map: 6 items, id = tid + it*512 -> c fast (bank-free writes)
    const float* gsrc[6];
    int loff[6];
    bool vld[6];
#pragma unroll
    for (int it = 0; it < 6; ++it) {
        int id = tid + it * 512;
        int c = id & 31, rq = id >> 5;            // rq < 96
        int row = rq / 24, q = rq - row * 24;     // row<4, q<24
        int r = h0 + row - 1;
        vld[it] = ((unsigned)r < 96u);
        int rs = vld[it] ? r : 0;
        gsrc[it] = xin + (size_t)b * 2359296 + (size_t)c * 9216 + rs * 96 + q * 4;
        loff[it] = (row * 98 + q * 4 + 1) * 40 + c;
    }

    f32x4 acc[4][6] = {};
    float4 f[6];

    // ---- prologue: issue A(step0), load+write B(chunk0)
    gl_lds16(wtr + aoff0, &Al[0][wv * 1024]);
    gl_lds16(wtr + aoff1, &Al[0][wv * 1024 + 512]);
#pragma unroll
    for (int it = 0; it < 6; ++it) f[it] = *(const float4*)gsrc[it];
#pragma unroll
    for (int it = 0; it < 6; ++it) {
        ushort u0 = 0, u1 = 0, u2 = 0, u3 = 0;
        if (vld[it]) { u0 = f2b(f[it].x); u1 = f2b(f[it].y);
                       u2 = f2b(f[it].z); u3 = f2b(f[it].w); }
        ushort* wp = &Bl[loff[it]];
        wp[0] = u0; wp[40] = u1; wp[80] = u2; wp[120] = u3;
    }
    __syncthreads();   // drains A(0) (vmcnt0) + B writes

    int stp = 0;
    for (int ch = 0; ch < 8; ++ch) {
        // issue next-chunk B loads early; they fly under 9 taps of MFMA
        if (ch < 7) {
#pragma unroll
            for (int it = 0; it < 6; ++it)
                f[it] = *(const float4*)(gsrc[it] + (size_t)(ch + 1) * 294912);
        }
#pragma unroll
        for (int tap = 0; tap < 9; ++tap, ++stp) {
            const int buf = stp & 1;
            if (stp < 71) {   // prefetch A(step+1) into other buffer
                const int nst = stp + 1;
                const int ntap = nst % 9, nch = nst / 9;
                const ushort* as = wtr + ntap * 65536 + nch * 32;
                gl_lds16(as + aoff0, &Al[buf ^ 1][wv * 1024]);
                gl_lds16(as + aoff1, &Al[buf ^ 1][wv * 1024 + 512]);
            }
            const int dy = tap / 3, dx = tap % 3;
            bf16x8 af[4], bfr[6];
            const ushort* Ab = &Al[buf][0];
#pragma unroll
            for (int mi = 0; mi < 4; ++mi)
                af[mi] = *(const bf16x8*)(Ab + (wm * 64 + mi * 16 + lo) * 32 + hi * 8);
            const ushort* Bp = &Bl[((wn + dy) * 98 + lo + dx) * 40 + hi * 8];
#pragma unroll
            for (int ni = 0; ni < 6; ++ni)
                bfr[ni] = *(const bf16x8*)(Bp + ni * 640);
#pragma unroll
            for (int mi = 0; mi < 4; ++mi)
#pragma unroll
                for (int ni = 0; ni < 6; ++ni)
                    acc[mi][ni] = __builtin_amdgcn_mfma_f32_16x16x32_bf16(
                        af[mi], bfr[ni], acc[mi][ni], 0, 0, 0);
            if (tap == 8) {
                if (ch < 7) {
                    __syncthreads();          // all waves done reading Bl
#pragma unroll
                    for (int it = 0; it < 6; ++it) {
                        ushort u0 = 0, u1 = 0, u2 = 0, u3 = 0;
                        if (vld[it]) { u0 = f2b(f[it].x); u1 = f2b(f[it].y);
                                       u2 = f2b(f[it].z); u3 = f2b(f[it].w); }
                        ushort* wp = &Bl[loff[it]];
                        wp[0] = u0; wp[40] = u1; wp[80] = u2; wp[120] = u3;
                    }
                    __syncthreads();          // B(ch+1) ready + A drained
                }
            } else {
                __syncthreads();              // A(step+1) drained, buffer swap safe
            }
        }
    }

    // epilogue: +bias, store y bf16 NCHW. D: col(px)=lane&15, row=hi*4+rr
    const size_t ybase = (size_t)b * 2359296 + (size_t)(h0 + wn) * 96;
#pragma unroll
    for (int mi = 0; mi < 4; ++mi) {
        const int o0 = wm * 64 + mi * 16 + hi * 4;
#pragma unroll
        for (int rr = 0; rr < 4; ++rr) {
            const int o = o0 + rr;
            const float bias = bc1[o];
#pragma unroll
            for (int ni = 0; ni < 6; ++ni) {
                const int px = ni * 16 + lo;
                yb[ybase + (size_t)o * 9216 + px] = f2b(acc[mi][ni][rr] + bias);
            }
        }
    }
}

// ---------------------------------------------------------------------------
// 5) BN stats: per-(b,c) partial sum/sumsq of y (deterministic, no atomics)
__global__ __launch_bounds__(256) void bnstat_k(const ushort* __restrict__ yb,
                                                float* __restrict__ part) {
    const int bc = blockIdx.x, tid = threadIdx.x;
    const ushort4* p4 = (const ushort4*)(yb + (size_t)bc * 9216);
    float s = 0.f, s2 = 0.f;
#pragma unroll
    for (int it = 0; it < 9; ++it) {
        ushort4 u = p4[tid + it * 256];
        float a = b2f(u.x), bb = b2f(u.y), c = b2f(u.z), d = b2f(u.w);
        s  += a + bb + c + d;
        s2 += a * a + bb * bb + c * c + d * d;
    }
    const int lane = tid & 63, wv = tid >> 6;
#pragma unroll
    for (int off = 32; off; off >>= 1) {
        s += __shfl_down(s, off);
        s2 += __shfl_down(s2, off);
    }
    __shared__ float r1[4], r2[4];
    if (lane == 0) { r1[wv] = s; r2[wv] = s2; }
    __syncthreads();
    if (tid == 0) part[bc]        = r1[0] + r1[1] + r1[2] + r1[3];
    if (tid == 1) part[4096 + bc] = r2[0] + r2[1] + r2[2] + r2[3];
}

// 6) finalize BN: scale/shift per channel
__global__ __launch_bounds__(256) void bnfin_k(const float* __restrict__ part,
                                               const float* __restrict__ gamma,
                                               const float* __restrict__ beta,
                                               float* __restrict__ bnp) {
    const int c = threadIdx.x;
    float s = 0.f, s2 = 0.f;
#pragma unroll
    for (int b = 0; b < 16; ++b) {
        s  += part[b * 256 + c];
        s2 += part[4096 + b * 256 + c];
    }
    const float invN = 1.0f / 147456.0f;
    float mu  = s * invN;
    float var = s2 * invN - mu * mu;
    float sc  = gamma[c] * rsqrtf(var + 1e-5f);
    bnp[c]       = sc;
    bnp[256 + c] = beta[c] - mu * sc;
}

// ---------------------------------------------------------------------------
// 7) depthwise 3x3 with per-(b,c) filters; BN+ReLU applied while staging plane
__global__ __launch_bounds__(256) void dw_k(const ushort* __restrict__ yb,
                                            const float* __restrict__ gen,
                                            const float* __restrict__ bnp,
                                            float* __restrict__ out) {
    __shared__ float pl[9216];
    const int bc = blockIdx.x, tid = threadIdx.x;
    const int c = bc & 255;
    const float sc = bnp[c], sh = bnp[256 + c];
    const ushort4* p4 = (const ushort4*)(yb + (size_t)bc * 9216);
#pragma unroll
    for (int it = 0; it < 9; ++it) {
        int v = tid + it * 256;
        ushort4 u = p4[v];
        float4 f;
        f.x = fmaxf(b2f(u.x) * sc + sh, 0.f);
        f.y = fmaxf(b2f(u.y) * sc + sh, 0.f);
        f.z = fmaxf(b2f(u.z) * sc + sh, 0.f);
        f.w = fmaxf(b2f(u.w) * sc + sh, 0.f);
        *(float4*)&pl[v * 4] = f;
    }
    float g[9];
    const float* gp = gen + (size_t)bc * 9;
#pragma unroll
    for (int k = 0; k < 9; ++k) g[k] = gp[k];
    __syncthreads();
    float* op = out + (size_t)bc * 9216;
#pragma unroll
    for (int it = 0; it < 36; ++it) {
        int i = tid + it * 256;
        int row = i / 96, col = i - row * 96;
        float a = 0.f;
#pragma unroll
        for (int dy = 0; dy < 3; ++dy) {
            int rr = row + dy - 1;
            if (rr < 0 || rr >= 96) continue;
#pragma unroll
            for (int dxq = 0; dxq < 3; ++dxq) {
                int cc = col + dxq - 1;
                if (cc < 0 || cc >= 96) continue;
                a += pl[rr * 96 + cc] * g[dy * 3 + dxq];
            }
        }
        op[i] = a;
    }
}

// ---------------------------------------------------------------------------
extern "C" void kernel_launch(void* const* d_in, const int* in_sizes, int n_in,
                              void* d_out, int out_size, void* d_ws, size_t ws_size,
                              hipStream_t stream) {
    const float* x       = (const float*)d_in[0];
    const float* conv_in = (const float*)d_in[1];
    const float* w_gen   = (const float*)d_in[2];
    const float* b_gen   = (const float*)d_in[3];
    const float* w_c1    = (const float*)d_in[4];
    const float* b_c1    = (const float*)d_in[5];
    const float* gamma   = (const float*)d_in[6];
    const float* beta    = (const float*)d_in[7];
    float* out = (float*)d_out;

    char* ws = (char*)d_ws;
    float*  pooled = (float*)(ws + 0);          // 147456 B
    float*  gen    = (float*)(ws + 147456);     // 147456 B
    ushort* wtr    = (ushort*)(ws + 294912);    // 1179648 B
    float*  part   = (float*)(ws + 1474560);    // 32768 B
    float*  bnp    = (float*)(ws + 1507328);    // 2048 B
    ushort* yb     = (ushort*)(ws + 1509376);   // 75497472 B  (total ~73.4 MB)

    pool_k  <<<4096, 256, 0, stream>>>(x, pooled);
    gen_k   <<<144,  256, 0, stream>>>(pooled, w_gen, b_gen, gen);
    wtr_k   <<<2304, 256, 0, stream>>>(w_c1, wtr);
    conv_k  <<<768,  512, 0, stream>>>(conv_in, wtr, b_c1, yb);
    bnstat_k<<<4096, 256, 0, stream>>>(yb, part);
    bnfin_k <<<1,    256, 0, stream>>>(part, gamma, beta, bnp);
    dw_k    <<<4096, 256, 0, stream>>>(yb, gen, bnp, out);
}